// Round 5
// baseline (251.236 us; speedup 1.0000x reference)
//
#include <hip/hip_runtime.h>
#include <math.h>

#define S 128
#define PI_F 3.14159265358979323846f

// ws layout (32-bit slots; int tables via cast):
//   WS_T1OFF  int[2500]   k1 x-gather offsets, pair-f'-indexed (+1 fold for 2nd l)
//   WS_T1AE   float[2500] k1 AFF env per pair-f'
//   WS_T2OFF  int[2500]   k_lat/k_corr gather offsets, quad-fp-indexed (+l fold)
//   WS_T2LE   float[2500] normalized LRI env per quad-fp
//   WS_LAT0P  float[23104] padded 152x152 relu(raw_aff-ada), halo = 0
//   WS_LATP   float[23104] padded 152x152 final lat, halo = 0.04
//   WS_PART   float[1024]  corr partials
#define WS_T1OFF 0
#define WS_T1AE  2500
#define WS_T2OFF 5000
#define WS_T2LE  7500
#define WS_LAT0P 10000
#define WS_LATP  33104
#define WS_PART  56208

// ---------------------------------------------------------------------------
// Setup: build all tables once + fill padded-array halos.  All later kernels
// do ZERO integer division / envelope math.
// ---------------------------------------------------------------------------
__global__ __launch_bounds__(256) void k_setup(float* __restrict__ wsf) {
    int* wsi = (int*)wsf;
    const int tid = threadIdx.x;
    __shared__ float s_le[625];
    __shared__ float s_red[4];

    float m = 0.0f;
    for (int r = tid; r < 625; r += 256) {
        float di = (float)(r / 25) - 12.0f;
        float dj = (float)(r % 25) - 12.0f;
        float d = sqrtf(di * di + dj * dj);
        float v = 0.0f;
        if (d < 12.5f) {
            float c1 = cosf(d * (PI_F / 25.0f));
            float inh = 0.0f;
            if (d < 4.5f) { float c2 = cosf(d * (PI_F / 9.0f)); inh = c2 * c2; }
            v = c1 * c1 * (1.0f - inh);
        }
        s_le[r] = v;
        m = fmaxf(m, v);
    }
    for (int off = 32; off > 0; off >>= 1) m = fmaxf(m, __shfl_down(m, off));
    if ((tid & 63) == 0) s_red[tid >> 6] = m;
    __syncthreads();
    const float inv = 1.0f / fmaxf(fmaxf(s_red[0], s_red[1]),
                                   fmaxf(s_red[2], s_red[3]));

    for (int fp = tid; fp < 2500; fp += 256) {
        // T1: pair-f' in [0,2500) -> (l in {2p,2p+1}, c, ki, kj)
        int half = fp >= 1250;
        int f = fp - 1250 * half;
        int c = f >= 625;
        int r = f - 625 * c;
        int ki = r / 25, kj = r - 25 * ki;
        wsi[WS_T1OFF + fp] = c * 23104 + ki * 152 + kj + half;
        float di = (float)ki - 12.0f, dj = (float)kj - 12.0f;
        float d = sqrtf(di * di + dj * dj);
        float ae = 0.0f;
        if (d < 12.5f) { float cc = cosf(d * (PI_F / 25.0f)); ae = cc * cc; }
        wsf[WS_T1AE + fp] = ae;
        // T2: quad-fp in [0,2500) -> (l = l0+fp/625, ki, kj), padded-152 gather
        int li_ = fp / 625;
        int r2 = fp - 625 * li_;
        int ki2 = r2 / 25, kj2 = r2 - 25 * ki2;
        wsi[WS_T2OFF + fp] = ki2 * 152 + kj2 + li_;
        wsf[WS_T2LE + fp] = s_le[r2] * inv;
    }
    for (int i = tid; i < 23104; i += 256) {
        wsf[WS_LAT0P + i] = 0.0f;
        wsf[WS_LATP + i] = 0.04f;
    }
}

// ---------------------------------------------------------------------------
// Kernel 1: tiles + raw_aff, one l-PAIR per block (alignment: rfs/tiles
// float4 at element 2500p).  Table-driven: per 4-element window just
// 2x ds_read_b128 + 4 L1 x-gathers + rfs4 + st4.  Store window is shifted
// by -1: t0 comes from __shfl_up of the neighbor's t4; lane-0 fallback is
// two scalar LDS reads; k==0 element is exactly 0 (envelope corner).
// ---------------------------------------------------------------------------
__global__ __launch_bounds__(256) void k_tiles_aff(const float* __restrict__ x,
                                                   const float* __restrict__ rfs,
                                                   const float* __restrict__ ada,
                                                   float* __restrict__ raw_aff,
                                                   float* __restrict__ tiles, // out+32769
                                                   float* __restrict__ wsf) {
    __shared__ int   s_off[2500];
    __shared__ float s_ae[2500];
    __shared__ float s_part[8];
    const int* wsi = (const int*)wsf;
    const int tid = threadIdx.x;
    const int lane = tid & 63;
    const int wv = tid >> 6;
    for (int i = tid; i < 2500; i += 256) {
        s_off[i] = wsi[WS_T1OFF + i];
        s_ae[i] = wsf[WS_T1AE + i];
    }
    __syncthreads();

    const int p = blockIdx.x;
    const int l0 = 2 * p;
    const int li = l0 >> 7, lj = l0 & 127;
    const float* __restrict__ xb = x + li * 152 + lj;
    const long pbase = (long)p * 2500;
    const float4* __restrict__ rfs4 = (const float4*)(rfs + pbase);
    float4* __restrict__ st4 = (float4*)(tiles + pbase - 1);   // 16B-aligned

    float acc0 = 0.0f, acc1 = 0.0f;
    for (int k = tid; k < 625; k += 256) {
        int4 o4 = *(const int4*)(s_off + 4 * k);
        float4 a4 = *(const float4*)(s_ae + 4 * k);
        float t1 = xb[o4.x] * a4.x;
        float t2 = xb[o4.y] * a4.y;
        float t3 = xb[o4.z] * a4.z;
        float t4 = xb[o4.w] * a4.w;
        float t0 = __shfl_up(t4, 1);
        if (lane == 0) {              // neighbor is cross-wave (or k==0)
            t0 = 0.0f;
            if (k > 0) t0 = xb[s_off[4 * k - 1]] * s_ae[4 * k - 1];
        }
        st4[k] = make_float4(t0, t1, t2, t3);
        float4 rv = rfs4[k];
        float c0 = t1 * fmaxf(rv.x, 0.f), c1 = t2 * fmaxf(rv.y, 0.f);
        float c2 = t3 * fmaxf(rv.z, 0.f), c3 = t4 * fmaxf(rv.w, 0.f);
        int fp = 4 * k;
        acc0 += (fp < 1250 ? c0 : 0.f) + (fp + 1 < 1250 ? c1 : 0.f)
              + (fp + 2 < 1250 ? c2 : 0.f) + (fp + 3 < 1250 ? c3 : 0.f);
        acc1 += (fp >= 1250 ? c0 : 0.f) + (fp + 1 >= 1250 ? c1 : 0.f)
              + (fp + 2 >= 1250 ? c2 : 0.f) + (fp + 3 >= 1250 ? c3 : 0.f);
    }
    if (p == 8191 && tid == 0) tiles[pbase + 2499] = 0.0f;  // env corner = 0

    for (int off = 32; off > 0; off >>= 1) {
        acc0 += __shfl_down(acc0, off);
        acc1 += __shfl_down(acc1, off);
    }
    if (lane == 0) { s_part[wv] = acc0; s_part[4 + wv] = acc1; }
    __syncthreads();
    if (tid == 0) {
        float ra0 = s_part[0] + s_part[1] + s_part[2] + s_part[3];
        float ra1 = s_part[4] + s_part[5] + s_part[6] + s_part[7];
        raw_aff[l0] = ra0;
        raw_aff[l0 + 1] = ra1;
        wsf[WS_LAT0P + (li + 12) * 152 + (lj + 12)] = fmaxf(ra0 - ada[l0], 0.0f);
        wsf[WS_LAT0P + (li + 12) * 152 + (lj + 13)] = fmaxf(ra1 - ada[l0 + 1], 0.0f);
    }
}

// 4-way accumulator select by quad-fp range (boundaries 625/1250/1875)
#define SEL4(fp_, c_)                                                     \
    {                                                                     \
        a0 += ((fp_) < 625) ? (c_) : 0.0f;                                \
        a1 += ((fp_) >= 625 && (fp_) < 1250) ? (c_) : 0.0f;               \
        a2 += ((fp_) >= 1250 && (fp_) < 1875) ? (c_) : 0.0f;              \
        a3 += ((fp_) >= 1875) ? (c_) : 0.0f;                              \
    }

// ---------------------------------------------------------------------------
// Kernel 2: final lat.  One wave per l-quad (lw float4 aligned at 2500q).
// Gather from PADDED lat0p (halo=0) -> no bounds checks, no divisions.
// latf[l] = tanh(relu(relu(aff) - lat_neg + aff)); also writes padded copy.
// ---------------------------------------------------------------------------
__global__ __launch_bounds__(256) void k_lat(const float* __restrict__ raw_aff,
                                             const float* __restrict__ ada,
                                             const float* __restrict__ lw,
                                             float* __restrict__ latf,
                                             float* __restrict__ wsf) {
    __shared__ int   s_off[2500];
    __shared__ float s_le[2500];
    const int* wsi = (const int*)wsf;
    const int tid = threadIdx.x;
    for (int i = tid; i < 2500; i += 256) {
        s_off[i] = wsi[WS_T2OFF + i];
        s_le[i] = wsf[WS_T2LE + i];
    }
    __syncthreads();

    const int lane = tid & 63, wv = tid >> 6;
    const int q = blockIdx.x * 4 + wv;
    const int l0 = 4 * q;
    const int li = l0 >> 7, lj = l0 & 127;
    const float* __restrict__ g = wsf + WS_LAT0P + li * 152 + lj;
    const float4* __restrict__ lw4 = (const float4*)(lw + (long)q * 2500);

    float a0 = 0.f, a1 = 0.f, a2 = 0.f, a3 = 0.f;
    for (int k = lane; k < 625; k += 64) {
        int4 o4 = *(const int4*)(s_off + 4 * k);
        float4 e4 = *(const float4*)(s_le + 4 * k);
        float4 w4 = lw4[k];
        float c0 = g[o4.x] * e4.x * fmaxf(w4.x, 0.f);
        float c1 = g[o4.y] * e4.y * fmaxf(w4.y, 0.f);
        float c2 = g[o4.z] * e4.z * fmaxf(w4.z, 0.f);
        float c3 = g[o4.w] * e4.w * fmaxf(w4.w, 0.f);
        int fp = 4 * k;
        SEL4(fp, c0); SEL4(fp + 1, c1); SEL4(fp + 2, c2); SEL4(fp + 3, c3);
    }
    for (int off = 32; off > 0; off >>= 1) {
        a0 += __shfl_down(a0, off); a1 += __shfl_down(a1, off);
        a2 += __shfl_down(a2, off); a3 += __shfl_down(a3, off);
    }
    if (lane == 0) {
        float acc[4] = { a0, a1, a2, a3 };
#pragma unroll
        for (int j = 0; j < 4; ++j) {
            int l = l0 + j;
            float aff_l = raw_aff[l] - ada[l];
            float v = fmaxf(aff_l, 0.0f) - acc[j] + aff_l;   // STRENGTH=1
            float lf = tanhf(fmaxf(v, 0.0f));
            latf[l] = lf;
            wsf[WS_LATP + (li + 12) * 152 + (lj + 12 + j)] = lf;
        }
    }
}

// ---------------------------------------------------------------------------
// Kernel 3: corr partials.  Same structure; gather from PADDED latp
// (halo = HOMEO_TARGET = 0.04).  One ws write per block.
// ---------------------------------------------------------------------------
__global__ __launch_bounds__(256) void k_corr(const float* __restrict__ latf,
                                              const float* __restrict__ lw,
                                              float* __restrict__ wsf) {
    __shared__ int   s_off[2500];
    __shared__ float s_le[2500];
    __shared__ float s_part[4];
    const int* wsi = (const int*)wsf;
    const int tid = threadIdx.x;
    for (int i = tid; i < 2500; i += 256) {
        s_off[i] = wsi[WS_T2OFF + i];
        s_le[i] = wsf[WS_T2LE + i];
    }
    __syncthreads();

    const int lane = tid & 63, wv = tid >> 6;
    const int q = blockIdx.x * 4 + wv;
    const int l0 = 4 * q;
    const int li = l0 >> 7, lj = l0 & 127;
    const float* __restrict__ g = wsf + WS_LATP + li * 152 + lj;
    const float4* __restrict__ lw4 = (const float4*)(lw + (long)q * 2500);

    float a0 = 0.f, a1 = 0.f, a2 = 0.f, a3 = 0.f;
    for (int k = lane; k < 625; k += 64) {
        int4 o4 = *(const int4*)(s_off + 4 * k);
        float4 e4 = *(const float4*)(s_le + 4 * k);
        float4 w4 = lw4[k];
        float c0 = g[o4.x] * e4.x * fmaxf(w4.x, 0.f);
        float c1 = g[o4.y] * e4.y * fmaxf(w4.y, 0.f);
        float c2 = g[o4.z] * e4.z * fmaxf(w4.z, 0.f);
        float c3 = g[o4.w] * e4.w * fmaxf(w4.w, 0.f);
        int fp = 4 * k;
        SEL4(fp, c0); SEL4(fp + 1, c1); SEL4(fp + 2, c2); SEL4(fp + 3, c3);
    }
    for (int off = 32; off > 0; off >>= 1) {
        a0 += __shfl_down(a0, off); a1 += __shfl_down(a1, off);
        a2 += __shfl_down(a2, off); a3 += __shfl_down(a3, off);
    }
    if (lane == 0) {
        s_part[wv] = a0 * latf[l0] + a1 * latf[l0 + 1]
                   + a2 * latf[l0 + 2] + a3 * latf[l0 + 3];
    }
    __syncthreads();
    if (tid == 0)
        wsf[WS_PART + blockIdx.x] = s_part[0] + s_part[1] + s_part[2] + s_part[3];
}

// ---------------------------------------------------------------------------
// Kernel 4: deterministic sum of 1024 partials -> corr scalar (runs last,
// overwriting the garbage k1 put in the corr slot).
// ---------------------------------------------------------------------------
__global__ __launch_bounds__(256) void k_reduce(const float* __restrict__ wsf,
                                                float* __restrict__ corr) {
    __shared__ float s_part[4];
    const int tid = threadIdx.x;
    const int lane = tid & 63, wv = tid >> 6;
    float acc = 0.0f;
    for (int i = tid; i < 1024; i += 256) acc += wsf[WS_PART + i];
    for (int off = 32; off > 0; off >>= 1) acc += __shfl_down(acc, off);
    if (lane == 0) s_part[wv] = acc;
    __syncthreads();
    if (tid == 0) corr[0] = s_part[0] + s_part[1] + s_part[2] + s_part[3];
}

// ---------------------------------------------------------------------------
// d_out layout (flat, return order):
//   [0, 16384)              raw_aff   [1,1,128,128]
//   [16384, 32768)          lat       [1,1,128,128]
//   [32768]                 lat_correlations (scalar)
//   [32769, 32769+20480000) tiles     [16384, 1, 1250]
// ---------------------------------------------------------------------------
extern "C" void kernel_launch(void* const* d_in, const int* in_sizes, int n_in,
                              void* d_out, int out_size, void* d_ws, size_t ws_size,
                              hipStream_t stream) {
    const float* x   = (const float*)d_in[0];   // [1,2,152,152]
    const float* rfs = (const float*)d_in[1];   // [16384,1250,1]
    const float* lw  = (const float*)d_in[2];   // [16384,625,1]
    const float* ada = (const float*)d_in[3];   // [1,1,128,128]

    float* out     = (float*)d_out;
    float* raw_aff = out;
    float* latf    = out + S * S;
    float* corr    = out + 2 * S * S;
    float* tiles   = out + 2 * S * S + 1;
    float* ws      = (float*)d_ws;

    k_setup<<<1, 256, 0, stream>>>(ws);
    k_tiles_aff<<<(S * S) / 2, 256, 0, stream>>>(x, rfs, ada, raw_aff, tiles, ws);
    k_lat<<<(S * S) / 16, 256, 0, stream>>>(raw_aff, ada, lw, latf, ws);
    k_corr<<<(S * S) / 16, 256, 0, stream>>>(latf, lw, ws);
    k_reduce<<<1, 256, 0, stream>>>(ws, corr);
}